// Round 2
// baseline (1939.522 us; speedup 1.0000x reference)
//
#include <hip/hip_runtime.h>
#include <hip/hip_bf16.h>
#include <math.h>

#define NR 4096
#define NSMP 32
#define NG 6
#define NP (NR*NSMP)        // 131072 points
#define NPS (NP*NG)         // 786432 gaussian samples
#define NL 10
#define TBL (1u<<21)
#define TMASK (TBL-1u)
#define PR1 2654435761u
#define PR2 805459861u

typedef __hip_bfloat16 bf16;

// ---------------- contraction: means/stds -> x01 in [0,1]^3 + scaled std ----
__global__ __launch_bounds__(256) void k_contract(const float* __restrict__ means,
                                                  const float* __restrict__ stds,
                                                  float4* __restrict__ ctr) {
    int i = blockIdx.x * 256 + threadIdx.x;
    if (i >= NPS) return;
    float x = means[i*3+0], y = means[i*3+1], z = means[i*3+2];
    float r2 = fmaxf(x*x + y*y + z*z, 1e-8f);
    float r  = sqrtf(r2);
    float f  = (2.f*r - 1.f) / r2;
    float zx, zy, zz, scale;
    if (r2 <= 1.f) { zx = x; zy = y; zz = z; scale = 1.f; }
    else { zx = f*x; zy = f*y; zz = f*z; scale = cbrtf(f*f / r2); }
    float s = stds[i] * scale * 0.5f;       // /2 (bound=2 rescale)
    // m = z/2; x01 = (m+1)/2 = z*0.25 + 0.5
    ctr[i] = make_float4(zx*0.25f + 0.5f, zy*0.25f + 0.5f, zz*0.25f + 0.5f, s);
}

// ---------------- hash-grid encode: one thread per (point, level) -----------
__global__ __launch_bounds__(256) void k_encode(const float4* __restrict__ ctr,
                                                const float* __restrict__ table,
                                                float4* __restrict__ feats) {
    int p = blockIdx.x * 256 + threadIdx.x;   // point
    int l = blockIdx.y;                       // level
    float res = (float)(16 << l);
    const float* tl = table + (size_t)l * TBL * 4u;
    float a0 = 0.f, a1 = 0.f, a2 = 0.f, a3 = 0.f;
    for (int s = 0; s < NG; s++) {
        float4 c = ctr[p*NG + s];
        float sr = c.w * res;
        float aw = erff(rsqrtf(8.f * sr * sr));
        float px = c.x*res, py = c.y*res, pz = c.z*res;
        float fx = floorf(px), fy = floorf(py), fz = floorf(pz);
        float rx = px - fx, ry = py - fy, rz = pz - fz;
        unsigned bx = (unsigned)fx, by = (unsigned)fy, bz = (unsigned)fz;
        unsigned hx[2] = { bx, bx + 1u };
        unsigned hy[2] = { by * PR1, (by + 1u) * PR1 };
        unsigned hz[2] = { bz * PR2, (bz + 1u) * PR2 };
        float wx[2] = { 1.f - rx, rx };
        float wy[2] = { 1.f - ry, ry };
        float wz[2] = { 1.f - rz, rz };
        #pragma unroll
        for (int cz = 0; cz < 2; cz++)
        #pragma unroll
        for (int cy = 0; cy < 2; cy++)
        #pragma unroll
        for (int cx = 0; cx < 2; cx++) {
            unsigned idx = (hx[cx] ^ hy[cy] ^ hz[cz]) & TMASK;
            float4 fv = *(const float4*)(tl + (size_t)idx * 4u);
            float w = wx[cx] * wy[cy] * wz[cz] * aw;
            a0 += w * fv.x; a1 += w * fv.y; a2 += w * fv.z; a3 += w * fv.w;
        }
    }
    const float inv = 1.f / 6.f;
    feats[(size_t)p * NL + l] = make_float4(a0*inv, a1*inv, a2*inv, a3*inv);
}

// ---------------- view-dir positional encoding ------------------------------
__global__ void k_dirs(const float* __restrict__ vd, float* __restrict__ de) {
    int r = blockIdx.x * 64 + threadIdx.x;
    if (r >= NR) return;
    float v0 = vd[r*3], v1 = vd[r*3+1], v2 = vd[r*3+2];
    float* o = de + r * 27;
    o[0] = v0; o[1] = v1; o[2] = v2;
    float v[3] = { v0, v1, v2 };
    #pragma unroll
    for (int sc = 0; sc < 4; sc++) {
        float scale = (float)(1 << sc);
        #pragma unroll
        for (int d = 0; d < 3; d++) {
            float xb = v[d] * scale;
            o[3  + sc*3 + d] = sinf(xb);
            o[15 + sc*3 + d] = cosf(xb);
        }
    }
}

// ---------------- generic tiled f32 GEMM with fused concat-A + epilogue -----
// LAYER 1: A=feats f32 [NP][40]           -> relu -> h1 bf16 [NP][64]
// LAYER 2: A=h1 bf16 [NP][64]             -> none -> x bf16 [NP][256] + density
// LAYER 3: A=[x(256)|de(27)]              -> relu -> y0 bf16 [NP][256]
// LAYER 4: A=[y0(256)|x(256)|de(27)]      -> relu -> y1 bf16 [NP][256]
template<int LAYER>
__global__ __launch_bounds__(256) void k_gemm(const float* __restrict__ Af,
                                              const bf16* __restrict__ Ab0,
                                              const bf16* __restrict__ Ab1,
                                              const float* __restrict__ de,
                                              const float* __restrict__ W,
                                              const float* __restrict__ bias,
                                              bf16* __restrict__ Cout,
                                              float* __restrict__ dens,
                                              int K, int N) {
    __shared__ float As[16][68];   // [k][m], padded
    __shared__ float Ws[16][64];   // [k][n]
    int tid = threadIdx.x;
    int tx = tid & 15, ty = tid >> 4;
    int m0 = blockIdx.x * 64, n0 = blockIdx.y * 64;
    float acc[4][4] = {};
    for (int kb = 0; kb < K; kb += 16) {
        #pragma unroll
        for (int i = 0; i < 4; i++) {
            int idx = tid + i * 256;
            int kk = idx & 15, mm = idx >> 4;
            int k = kb + kk;
            float v = 0.f;
            if (k < K) {
                int m = m0 + mm;
                if constexpr (LAYER == 1) {
                    v = Af[m * 40 + k];
                } else if constexpr (LAYER == 2) {
                    v = __bfloat162float(Ab0[(size_t)m * 64 + k]);
                } else if constexpr (LAYER == 3) {
                    v = (k < 256) ? __bfloat162float(Ab0[(size_t)m * 256 + k])
                                  : de[(m >> 5) * 27 + (k - 256)];
                } else {
                    if (k < 256)      v = __bfloat162float(Ab0[(size_t)m * 256 + k]);
                    else if (k < 512) v = __bfloat162float(Ab1[(size_t)m * 256 + (k - 256)]);
                    else              v = de[(m >> 5) * 27 + (k - 512)];
                }
            }
            As[kk][mm] = v;
        }
        #pragma unroll
        for (int i = 0; i < 4; i++) {
            int idx = tid + i * 256;
            int c = idx & 63, rr = idx >> 6;
            int k = kb + rr;
            Ws[rr][c] = (k < K) ? W[(size_t)k * N + n0 + c] : 0.f;
        }
        __syncthreads();
        #pragma unroll
        for (int kk = 0; kk < 16; kk++) {
            float4 a = *(const float4*)&As[kk][ty * 4];
            float4 b = *(const float4*)&Ws[kk][tx * 4];
            float av[4] = { a.x, a.y, a.z, a.w };
            float bv[4] = { b.x, b.y, b.z, b.w };
            #pragma unroll
            for (int i2 = 0; i2 < 4; i2++)
            #pragma unroll
            for (int j = 0; j < 4; j++)
                acc[i2][j] += av[i2] * bv[j];
        }
        __syncthreads();
    }
    #pragma unroll
    for (int i = 0; i < 4; i++) {
        int m = m0 + ty * 4 + i;
        #pragma unroll
        for (int j = 0; j < 4; j++) {
            int n = n0 + tx * 4 + j;
            float v = acc[i][j] + bias[n];
            if constexpr (LAYER == 2) {
                if (n == 0) {   // density = softplus(x[...,0] - 1) from f32 acc
                    float t = v - 1.f;
                    dens[(size_t)m * 4] = (t > 20.f) ? t : log1pf(expf(t));
                }
            } else {
                v = fmaxf(v, 0.f);
            }
            Cout[(size_t)m * N + n] = __float2bfloat16(v);
        }
    }
}

// ---------------- final rgb layer (K=256, N=3) + sigmoid + padding ----------
__global__ __launch_bounds__(256) void k_l5(const bf16* __restrict__ y1,
                                            const float* __restrict__ Wrgb,
                                            const float* __restrict__ brgb,
                                            float* __restrict__ out) {
    int gid = blockIdx.x * 256 + threadIdx.x;
    int p = gid >> 2, c = gid & 3;
    if (p >= NP || c >= 3) return;
    float acc = brgb[c];
    const bf16* row = y1 + (size_t)p * 256;
    for (int k = 0; k < 256; k++)
        acc += __bfloat162float(row[k]) * Wrgb[k * 3 + c];
    float sg = 1.f / (1.f + expf(-acc));
    out[(size_t)p * 4 + 1 + c] = sg * 1.002f - 0.001f;
}

extern "C" void kernel_launch(void* const* d_in, const int* in_sizes, int n_in,
                              void* d_out, int out_size, void* d_ws, size_t ws_size,
                              hipStream_t stream) {
    const float* means = (const float*)d_in[0];
    const float* stds  = (const float*)d_in[1];
    const float* vd    = (const float*)d_in[2];
    const float* table = (const float*)d_in[3];
    const float* W1    = (const float*)d_in[4];
    const float* b1    = (const float*)d_in[5];
    const float* W2    = (const float*)d_in[6];
    const float* b2    = (const float*)d_in[7];
    const float* Wd0   = (const float*)d_in[8];
    const float* bd0   = (const float*)d_in[9];
    const float* Wd1   = (const float*)d_in[10];
    const float* bd1   = (const float*)d_in[11];
    const float* Wrgb  = (const float*)d_in[12];
    const float* brgb  = (const float*)d_in[13];
    float* out = (float*)d_out;

    char* ws = (char*)d_ws;
    float4* ctr   = (float4*)(ws);                 // 786432*16  = 12,582,912
    float4* feats = (float4*)(ws + 12582912);      // 131072*40*4= 20,971,520
    float*  de    = (float*) (ws + 33554432);      // 4096*27*4  =    442,368
    bf16*   h1    = (bf16*)  (ws + 33996800);      // 131072*64*2= 16,777,216
    bf16*   x     = (bf16*)  (ws + 50774016);      // 131072*256*2=67,108,864
    bf16*   y0    = (bf16*)  (ws + 117882880);     // 67,108,864
    bf16*   y1    = (bf16*)  (ws + 184991744);     // 67,108,864  (total ~252MB)

    k_contract<<<dim3(NPS/256), 256, 0, stream>>>(means, stds, ctr);
    k_encode<<<dim3(NP/256, NL), 256, 0, stream>>>(ctr, table, feats);
    k_dirs<<<dim3(NR/64), 64, 0, stream>>>(vd, de);
    k_gemm<1><<<dim3(NP/64, 1), 256, 0, stream>>>((const float*)feats, nullptr, nullptr, de, W1, b1, h1, nullptr, 40, 64);
    k_gemm<2><<<dim3(NP/64, 4), 256, 0, stream>>>(nullptr, h1, nullptr, de, W2, b2, x, out, 64, 256);
    k_gemm<3><<<dim3(NP/64, 4), 256, 0, stream>>>(nullptr, x, nullptr, de, Wd0, bd0, y0, nullptr, 283, 256);
    k_gemm<4><<<dim3(NP/64, 4), 256, 0, stream>>>(nullptr, y0, x, de, Wd1, bd1, y1, nullptr, 539, 256);
    k_l5<<<dim3(NP*4/256), 256, 0, stream>>>(y1, Wrgb, brgb, out);
}

// Round 6
// 1164.042 us; speedup vs baseline: 1.6662x; 1.6662x over previous
//
#include <hip/hip_runtime.h>
#include <hip/hip_bf16.h>
#include <math.h>
#include <string.h>

#define NR 4096
#define NSMP 32
#define NG 6
#define NP (NR*NSMP)        // 131072 points
#define NPS (NP*NG)         // 786432 gaussian samples
#define NL 10
#define TBL (1u<<21)
#define TMASK (TBL-1u)
#define PR1 2654435761u
#define PR2 805459861u

typedef __hip_bfloat16 bf16;
typedef __attribute__((ext_vector_type(8))) short short8;
typedef __attribute__((ext_vector_type(4))) float f32x4;

__device__ inline short f2bf_bits(float f) {
    __hip_bfloat16 h = __float2bfloat16(f);
    return (short)__builtin_bit_cast(unsigned short, h);
}

// ---------------- contraction: means/stds -> x01 in [0,1]^3 + scaled std ----
__global__ __launch_bounds__(256) void k_contract(const float* __restrict__ means,
                                                  const float* __restrict__ stds,
                                                  float4* __restrict__ ctr) {
    int i = blockIdx.x * 256 + threadIdx.x;
    if (i >= NPS) return;
    float x = means[i*3+0], y = means[i*3+1], z = means[i*3+2];
    float r2 = fmaxf(x*x + y*y + z*z, 1e-8f);
    float r  = sqrtf(r2);
    float f  = (2.f*r - 1.f) / r2;
    float zx, zy, zz, scale;
    if (r2 <= 1.f) { zx = x; zy = y; zz = z; scale = 1.f; }
    else { zx = f*x; zy = f*y; zz = f*z; scale = cbrtf(f*f / r2); }
    float s = stds[i] * scale * 0.5f;
    ctr[i] = make_float4(zx*0.25f + 0.5f, zy*0.25f + 0.5f, zz*0.25f + 0.5f, s);
}

// ---------------- hash-grid encode: one thread per (point, level) -----------
__global__ __launch_bounds__(256) void k_encode(const float4* __restrict__ ctr,
                                                const float* __restrict__ table,
                                                float4* __restrict__ feats) {
    int p = blockIdx.x * 256 + threadIdx.x;
    int l = blockIdx.y;
    float res = (float)(16 << l);
    const float* tl = table + (size_t)l * TBL * 4u;
    float a0 = 0.f, a1 = 0.f, a2 = 0.f, a3 = 0.f;
    for (int s = 0; s < NG; s++) {
        float4 c = ctr[p*NG + s];
        float sr = c.w * res;
        float aw = erff(rsqrtf(8.f * sr * sr));
        float px = c.x*res, py = c.y*res, pz = c.z*res;
        float fx = floorf(px), fy = floorf(py), fz = floorf(pz);
        float rx = px - fx, ry = py - fy, rz = pz - fz;
        unsigned bx = (unsigned)fx, by = (unsigned)fy, bz = (unsigned)fz;
        unsigned hx[2] = { bx, bx + 1u };
        unsigned hy[2] = { by * PR1, (by + 1u) * PR1 };
        unsigned hz[2] = { bz * PR2, (bz + 1u) * PR2 };
        float wx[2] = { 1.f - rx, rx };
        float wy[2] = { 1.f - ry, ry };
        float wz[2] = { 1.f - rz, rz };
        #pragma unroll
        for (int cz = 0; cz < 2; cz++)
        #pragma unroll
        for (int cy = 0; cy < 2; cy++)
        #pragma unroll
        for (int cx = 0; cx < 2; cx++) {
            unsigned idx = (hx[cx] ^ hy[cy] ^ hz[cz]) & TMASK;
            float4 fv = *(const float4*)(tl + (size_t)idx * 4u);
            float w = wx[cx] * wy[cy] * wz[cz] * aw;
            a0 += w * fv.x; a1 += w * fv.y; a2 += w * fv.z; a3 += w * fv.w;
        }
    }
    const float inv = 1.f / 6.f;
    feats[(size_t)p * NL + l] = make_float4(a0*inv, a1*inv, a2*inv, a3*inv);
}

// ---------------- view-dir positional encoding ------------------------------
__global__ void k_dirs(const float* __restrict__ vd, float* __restrict__ de) {
    int r = blockIdx.x * 64 + threadIdx.x;
    if (r >= NR) return;
    float v0 = vd[r*3], v1 = vd[r*3+1], v2 = vd[r*3+2];
    float* o = de + r * 27;
    o[0] = v0; o[1] = v1; o[2] = v2;
    float v[3] = { v0, v1, v2 };
    #pragma unroll
    for (int sc = 0; sc < 4; sc++) {
        float scale = (float)(1 << sc);
        #pragma unroll
        for (int d = 0; d < 3; d++) {
            float xb = v[d] * scale;
            o[3  + sc*3 + d] = sinf(xb);
            o[15 + sc*3 + d] = cosf(xb);
        }
    }
}

// ---------------- layer 1: f32 VALU GEMM (K=40, N=64) -----------------------
__global__ __launch_bounds__(256) void k_l1(const float* __restrict__ Af,
                                            const float* __restrict__ W,
                                            const float* __restrict__ bias,
                                            bf16* __restrict__ Cout) {
    const int K = 40, N = 64;
    __shared__ float As[16][68];
    __shared__ float Ws[16][64];
    int tid = threadIdx.x;
    int tx = tid & 15, ty = tid >> 4;
    int m0 = blockIdx.x * 64;
    float acc[4][4] = {};
    for (int kb = 0; kb < K; kb += 16) {
        #pragma unroll
        for (int i = 0; i < 4; i++) {
            int idx = tid + i * 256;
            int kk = idx & 15, mm = idx >> 4;
            int k = kb + kk;
            As[kk][mm] = (k < K) ? Af[(size_t)(m0 + mm) * 40 + k] : 0.f;
        }
        #pragma unroll
        for (int i = 0; i < 4; i++) {
            int idx = tid + i * 256;
            int c = idx & 63, rr = idx >> 6;
            int k = kb + rr;
            Ws[rr][c] = (k < K) ? W[(size_t)k * N + c] : 0.f;
        }
        __syncthreads();
        #pragma unroll
        for (int kk = 0; kk < 16; kk++) {
            float4 a = *(const float4*)&As[kk][ty * 4];
            float4 b = *(const float4*)&Ws[kk][tx * 4];
            float av[4] = { a.x, a.y, a.z, a.w };
            float bv[4] = { b.x, b.y, b.z, b.w };
            #pragma unroll
            for (int i2 = 0; i2 < 4; i2++)
            #pragma unroll
            for (int j = 0; j < 4; j++)
                acc[i2][j] += av[i2] * bv[j];
        }
        __syncthreads();
    }
    #pragma unroll
    for (int i = 0; i < 4; i++) {
        int m = m0 + ty * 4 + i;
        #pragma unroll
        for (int j = 0; j < 4; j++) {
            int n = tx * 4 + j;
            float v = fmaxf(acc[i][j] + bias[n], 0.f);
            Cout[(size_t)m * N + n] = __float2bfloat16(v);
        }
    }
}

// ---------------- weight prep: f32 [K][256] -> bf16 [256][Kpad] -------------
__global__ __launch_bounds__(256) void k_prepw(const float* __restrict__ W2,
                                               const float* __restrict__ Wd0,
                                               const float* __restrict__ Wd1,
                                               short* __restrict__ Wt2,
                                               short* __restrict__ Wt3,
                                               short* __restrict__ Wt4) {
    int i = blockIdx.x * 256 + threadIdx.x;
    if (i < 256*64) {
        int n = i >> 6, k = i & 63;
        Wt2[i] = f2bf_bits(W2[(size_t)k*256 + n]);
        return;
    }
    i -= 256*64;
    if (i < 256*320) {
        int n = i / 320, k = i % 320;
        Wt3[i] = f2bf_bits(k < 283 ? Wd0[(size_t)k*256 + n] : 0.f);
        return;
    }
    i -= 256*320;
    if (i < 256*576) {
        int n = i / 576, k = i % 576;
        Wt4[i] = f2bf_bits(k < 539 ? Wd1[(size_t)k*256 + n] : 0.f);
    }
}

// ---------------- staging chunk loader (8 bf16 = 16B) ------------------------
template<int LAYER>
__device__ inline short8 load_chunk(const short* __restrict__ A0,
                                    const short* __restrict__ A1,
                                    const float* __restrict__ de,
                                    int m, int k) {
    if constexpr (LAYER == 2) {
        return *(const short8*)(A0 + (size_t)m * 64 + k);
    } else if constexpr (LAYER == 3) {
        if (k < 256) return *(const short8*)(A0 + (size_t)m * 256 + k);
        short8 v;
        int ray = m >> 5;
        #pragma unroll
        for (int j = 0; j < 8; j++) {
            int kk = k + j - 256;
            v[j] = f2bf_bits((kk < 27) ? de[ray * 27 + kk] : 0.f);
        }
        return v;
    } else {
        if (k < 256) return *(const short8*)(A0 + (size_t)m * 256 + k);
        if (k < 512) return *(const short8*)(A1 + (size_t)m * 256 + (k - 256));
        short8 v;
        int ray = m >> 5;
        #pragma unroll
        for (int j = 0; j < 8; j++) {
            int kk = k + j - 512;
            v[j] = f2bf_bits((kk < 27) ? de[ray * 27 + kk] : 0.f);
        }
        return v;
    }
}

// ---------------- MFMA MLP layer: [NP][K] @ Wt[256][Kp] -> [NP][256] ---------
// LAYER 2: A=h1[NP][64],      out x + density   (no relu)
// LAYER 3: A=[x|de] Kp=320,   out y0 (relu)
// LAYER 4: A=[y0|x|de] Kp=576 out y1 (relu)
template<int LAYER>
__global__ __launch_bounds__(256) void k_mlp(const short* __restrict__ A0,
                                             const short* __restrict__ A1,
                                             const float* __restrict__ de,
                                             const short* __restrict__ Wt,
                                             const float* __restrict__ bias,
                                             short* __restrict__ Cout,
                                             float* __restrict__ dens) {
    constexpr int KP = (LAYER == 2) ? 64 : (LAYER == 3) ? 320 : 576;
    __shared__ __align__(16) char As[8192];   // 64 rows x 64 k bf16, XOR-swizzled
    int tid = threadIdx.x;
    int wid = tid >> 6, lane = tid & 63;
    int m0 = blockIdx.x * 64;
    int l15 = lane & 15, l4 = lane >> 4;

    f32x4 acc[4][4] = {};
    for (int kt = 0; kt < KP / 64; kt++) {
        #pragma unroll
        for (int i = 0; i < 2; i++) {
            int q = tid + i * 256;
            int m = q >> 3, k8 = q & 7;
            short8 v = load_chunk<LAYER>(A0, A1, de, m0 + m, kt * 64 + k8 * 8);
            *(short8*)(As + ((m * 128 + k8 * 16) ^ ((m & 7) << 4))) = v;
        }
        __syncthreads();
        #pragma unroll
        for (int ks = 0; ks < 2; ks++) {
            short8 bfr[4], afr[4];
            #pragma unroll
            for (int nf = 0; nf < 4; nf++)
                bfr[nf] = *(const short8*)(Wt + (size_t)(wid * 64 + nf * 16 + l15) * KP
                                              + kt * 64 + ks * 32 + l4 * 8);
            #pragma unroll
            for (int mf = 0; mf < 4; mf++) {
                int m = mf * 16 + l15;
                afr[mf] = *(const short8*)(As + ((m * 128 + (ks * 4 + l4) * 16) ^ ((m & 7) << 4)));
            }
            #pragma unroll
            for (int mf = 0; mf < 4; mf++)
            #pragma unroll
            for (int nf = 0; nf < 4; nf++)
                acc[mf][nf] = __builtin_amdgcn_mfma_f32_16x16x32_bf16(afr[mf], bfr[nf], acc[mf][nf], 0, 0, 0);
        }
        __syncthreads();
    }

    #pragma unroll
    for (int mf = 0; mf < 4; mf++) {
        #pragma unroll
        for (int nf = 0; nf < 4; nf++) {
            int col = wid * 64 + nf * 16 + l15;
            float b = bias[col];
            #pragma unroll
            for (int r = 0; r < 4; r++) {
                int row = m0 + mf * 16 + l4 * 4 + r;
                float v = acc[mf][nf][r] + b;
                if constexpr (LAYER == 2) {
                    if (col == 0) {
                        float t = v - 1.f;
                        dens[(size_t)row * 4] = (t > 20.f) ? t : log1pf(expf(t));
                    }
                } else {
                    v = fmaxf(v, 0.f);
                }
                Cout[(size_t)row * 256 + col] = f2bf_bits(v);
            }
        }
    }
}

// ---------------- rgb layer: wave per point, shuffle reduce ------------------
__global__ __launch_bounds__(256) void k_rgb(const short* __restrict__ y1,
                                             const float* __restrict__ Wrgb,
                                             const float* __restrict__ brgb,
                                             float* __restrict__ out) {
    typedef __attribute__((ext_vector_type(4))) short short4v;
    int lane = threadIdx.x & 63;
    int p = blockIdx.x * 4 + (threadIdx.x >> 6);
    short4v yv = *(const short4v*)(y1 + (size_t)p * 256 + lane * 4);
    float y[4];
    #pragma unroll
    for (int j = 0; j < 4; j++) {
        unsigned u = ((unsigned)(unsigned short)yv[j]) << 16;
        y[j] = __builtin_bit_cast(float, u);
    }
    // Wrgb [256][3] f32: rows lane*4..+3 = 12 contiguous floats
    float4 w0 = *(const float4*)(Wrgb + lane * 12);
    float4 w1 = *(const float4*)(Wrgb + lane * 12 + 4);
    float4 w2 = *(const float4*)(Wrgb + lane * 12 + 8);
    float wf[12] = { w0.x, w0.y, w0.z, w0.w, w1.x, w1.y, w1.z, w1.w, w2.x, w2.y, w2.z, w2.w };
    float a0 = 0.f, a1 = 0.f, a2 = 0.f;
    #pragma unroll
    for (int j = 0; j < 4; j++) {
        a0 += y[j] * wf[j*3 + 0];
        a1 += y[j] * wf[j*3 + 1];
        a2 += y[j] * wf[j*3 + 2];
    }
    #pragma unroll
    for (int off = 32; off > 0; off >>= 1) {
        a0 += __shfl_xor(a0, off);
        a1 += __shfl_xor(a1, off);
        a2 += __shfl_xor(a2, off);
    }
    if (lane == 0) {
        float s0 = 1.f / (1.f + expf(-(a0 + brgb[0])));
        float s1 = 1.f / (1.f + expf(-(a1 + brgb[1])));
        float s2 = 1.f / (1.f + expf(-(a2 + brgb[2])));
        out[(size_t)p * 4 + 1] = s0 * 1.002f - 0.001f;
        out[(size_t)p * 4 + 2] = s1 * 1.002f - 0.001f;
        out[(size_t)p * 4 + 3] = s2 * 1.002f - 0.001f;
    }
}

extern "C" void kernel_launch(void* const* d_in, const int* in_sizes, int n_in,
                              void* d_out, int out_size, void* d_ws, size_t ws_size,
                              hipStream_t stream) {
    const float* means = (const float*)d_in[0];
    const float* stds  = (const float*)d_in[1];
    const float* vd    = (const float*)d_in[2];
    const float* table = (const float*)d_in[3];
    const float* W1    = (const float*)d_in[4];
    const float* b1    = (const float*)d_in[5];
    const float* W2    = (const float*)d_in[6];
    const float* b2    = (const float*)d_in[7];
    const float* Wd0   = (const float*)d_in[8];
    const float* bd0   = (const float*)d_in[9];
    const float* Wd1   = (const float*)d_in[10];
    const float* bd1   = (const float*)d_in[11];
    const float* Wrgb  = (const float*)d_in[12];
    const float* brgb  = (const float*)d_in[13];
    float* out = (float*)d_out;

    char* ws = (char*)d_ws;
    float4* ctr   = (float4*)(ws);                 // 786432*16  = 12,582,912 (dead after encode)
    float4* feats = (float4*)(ws + 12582912);      // 131072*40*4= 20,971,520
    float*  de    = (float*) (ws + 33554432);      //    442,368
    short*  h1    = (short*) (ws + 33996800);      // 16,777,216
    short*  x     = (short*) (ws + 50774016);      // 67,108,864
    short*  y0    = (short*) (ws + 117882880);     // 67,108,864
    short*  y1    = (short*) (ws + 184991744);     // 67,108,864
    // bf16 weights live in the (dead-after-encode) ctr region
    short*  Wt2   = (short*)(ws);                  //  32,768
    short*  Wt3   = (short*)(ws + 32768);          // 163,840
    short*  Wt4   = (short*)(ws + 196608);         // 294,912  (end 491,520 < 12.58MB)

    k_contract<<<dim3(NPS/256), 256, 0, stream>>>(means, stds, ctr);
    k_encode<<<dim3(NP/256, NL), 256, 0, stream>>>(ctr, table, feats);
    k_dirs<<<dim3(NR/64), 64, 0, stream>>>(vd, de);
    k_prepw<<<dim3(960), 256, 0, stream>>>(W2, Wd0, Wd1, Wt2, Wt3, Wt4);
    k_l1<<<dim3(NP/64), 256, 0, stream>>>((const float*)feats, W1, b1, (bf16*)h1);
    k_mlp<2><<<dim3(NP/64), 256, 0, stream>>>(h1, nullptr, nullptr, Wt2, b2, x, out);
    k_mlp<3><<<dim3(NP/64), 256, 0, stream>>>(x, nullptr, de, Wt3, bd0, y0, nullptr);
    k_mlp<4><<<dim3(NP/64), 256, 0, stream>>>(y0, x, de, Wt4, bd1, y1, nullptr);
    k_rgb<<<dim3(NP/4), 256, 0, stream>>>(y1, Wrgb, brgb, out);
}

// Round 10
// 1147.149 us; speedup vs baseline: 1.6907x; 1.0147x over previous
//
#include <hip/hip_runtime.h>
#include <hip/hip_bf16.h>
#include <math.h>
#include <string.h>

#define NR 4096
#define NSMP 32
#define NG 6
#define NP (NR*NSMP)        // 131072 points
#define NPS (NP*NG)         // 786432 gaussian samples
#define NL 10
#define TBL (1u<<21)
#define TMASK (TBL-1u)
#define PR1 2654435761u
#define PR2 805459861u
#define HLV0 3              // first bf16-quantized level
#define NHL (NL - HLV0)     // 7 quantized levels

typedef __hip_bfloat16 bf16;
typedef __attribute__((ext_vector_type(8))) short short8;
typedef __attribute__((ext_vector_type(4))) float f32x4;

__device__ inline short f2bf_bits(float f) {
    __hip_bfloat16 h = __float2bfloat16(f);
    return (short)__builtin_bit_cast(unsigned short, h);
}
__device__ inline float bfbits2f(unsigned short u) {
    return __builtin_bit_cast(float, ((unsigned)u) << 16);
}

// ---------------- contraction: means/stds -> x01 in [0,1]^3 + scaled std ----
__global__ __launch_bounds__(256) void k_contract(const float* __restrict__ means,
                                                  const float* __restrict__ stds,
                                                  float4* __restrict__ ctr) {
    int i = blockIdx.x * 256 + threadIdx.x;
    if (i >= NPS) return;
    float x = means[i*3+0], y = means[i*3+1], z = means[i*3+2];
    float r2 = fmaxf(x*x + y*y + z*z, 1e-8f);
    float r  = sqrtf(r2);
    float f  = (2.f*r - 1.f) / r2;
    float zx, zy, zz, scale;
    if (r2 <= 1.f) { zx = x; zy = y; zz = z; scale = 1.f; }
    else { zx = f*x; zy = f*y; zz = f*z; scale = cbrtf(f*f / r2); }
    float s = stds[i] * scale * 0.5f;
    ctr[i] = make_float4(zx*0.25f + 0.5f, zy*0.25f + 0.5f, zz*0.25f + 0.5f, s);
}

// ---------------- table prep: levels 3..9 f32 -> bf16 (ushort4/entry) -------
__global__ __launch_bounds__(256) void k_prept(const float* __restrict__ table,
                                               ushort4* __restrict__ th) {
    size_t i = ((size_t)blockIdx.x * 256 + threadIdx.x) * 2;   // entry index
    const float4* src = (const float4*)(table + (size_t)HLV0 * TBL * 4u);
    #pragma unroll
    for (int j = 0; j < 2; j++) {
        float4 v = src[i + j];
        ushort4 o;
        o.x = (unsigned short)f2bf_bits(v.x);
        o.y = (unsigned short)f2bf_bits(v.y);
        o.z = (unsigned short)f2bf_bits(v.z);
        o.w = (unsigned short)f2bf_bits(v.w);
        th[i + j] = o;
    }
}

// ---------------- hash-grid encode: one thread per (point, level) -----------
// BASE=0,HI=false: levels 0..2 read f32 table (hot set is cache-resident)
// BASE=3,HI=true : levels 3..9 read bf16 table (112 MB, L3-resident)
template<int BASE, bool HI>
__global__ __launch_bounds__(256) void k_encode(const float4* __restrict__ ctr,
                                                const float* __restrict__ table,
                                                const ushort4* __restrict__ th,
                                                float4* __restrict__ feats) {
    int p = blockIdx.x * 256 + threadIdx.x;
    int l = BASE + blockIdx.y;
    float res = (float)(16 << l);
    const float4* tf = (const float4*)(table + (size_t)l * TBL * 4u);
    const ushort4* thl = th + (size_t)(l - HLV0) * TBL;
    float a0 = 0.f, a1 = 0.f, a2 = 0.f, a3 = 0.f;
    #pragma unroll
    for (int s = 0; s < NG; s++) {
        float4 c = ctr[p*NG + s];
        float sr = c.w * res;
        float aw = erff(rsqrtf(8.f * sr * sr));
        float px = c.x*res, py = c.y*res, pz = c.z*res;
        float fx = floorf(px), fy = floorf(py), fz = floorf(pz);
        float rx = px - fx, ry = py - fy, rz = pz - fz;
        unsigned bx = (unsigned)fx, by = (unsigned)fy, bz = (unsigned)fz;
        unsigned hx[2] = { bx, bx + 1u };
        unsigned hy[2] = { by * PR1, (by + 1u) * PR1 };
        unsigned hz[2] = { bz * PR2, (bz + 1u) * PR2 };
        float wx[2] = { 1.f - rx, rx };
        float wy[2] = { 1.f - ry, ry };
        float wz[2] = { 1.f - rz, rz };
        #pragma unroll
        for (int cz = 0; cz < 2; cz++)
        #pragma unroll
        for (int cy = 0; cy < 2; cy++)
        #pragma unroll
        for (int cx = 0; cx < 2; cx++) {
            unsigned idx = (hx[cx] ^ hy[cy] ^ hz[cz]) & TMASK;
            float v0, v1, v2, v3;
            if constexpr (HI) {
                ushort4 e = thl[idx];
                v0 = bfbits2f(e.x); v1 = bfbits2f(e.y);
                v2 = bfbits2f(e.z); v3 = bfbits2f(e.w);
            } else {
                float4 fv = tf[idx];
                v0 = fv.x; v1 = fv.y; v2 = fv.z; v3 = fv.w;
            }
            float w = wx[cx] * wy[cy] * wz[cz] * aw;
            a0 += w * v0; a1 += w * v1; a2 += w * v2; a3 += w * v3;
        }
    }
    const float inv = 1.f / 6.f;
    feats[(size_t)p * NL + l] = make_float4(a0*inv, a1*inv, a2*inv, a3*inv);
}

// ---------------- view-dir positional encoding ------------------------------
__global__ void k_dirs(const float* __restrict__ vd, float* __restrict__ de) {
    int r = blockIdx.x * 64 + threadIdx.x;
    if (r >= NR) return;
    float v0 = vd[r*3], v1 = vd[r*3+1], v2 = vd[r*3+2];
    float* o = de + r * 27;
    o[0] = v0; o[1] = v1; o[2] = v2;
    float v[3] = { v0, v1, v2 };
    #pragma unroll
    for (int sc = 0; sc < 4; sc++) {
        float scale = (float)(1 << sc);
        #pragma unroll
        for (int d = 0; d < 3; d++) {
            float xb = v[d] * scale;
            o[3  + sc*3 + d] = sinf(xb);
            o[15 + sc*3 + d] = cosf(xb);
        }
    }
}

// ---------------- layer 1: f32 VALU GEMM (K=40, N=64) -----------------------
__global__ __launch_bounds__(256) void k_l1(const float* __restrict__ Af,
                                            const float* __restrict__ W,
                                            const float* __restrict__ bias,
                                            bf16* __restrict__ Cout) {
    const int K = 40, N = 64;
    __shared__ float As[16][68];
    __shared__ float Ws[16][64];
    int tid = threadIdx.x;
    int tx = tid & 15, ty = tid >> 4;
    int m0 = blockIdx.x * 64;
    float acc[4][4] = {};
    for (int kb = 0; kb < K; kb += 16) {
        #pragma unroll
        for (int i = 0; i < 4; i++) {
            int idx = tid + i * 256;
            int kk = idx & 15, mm = idx >> 4;
            int k = kb + kk;
            As[kk][mm] = (k < K) ? Af[(size_t)(m0 + mm) * 40 + k] : 0.f;
        }
        #pragma unroll
        for (int i = 0; i < 4; i++) {
            int idx = tid + i * 256;
            int c = idx & 63, rr = idx >> 6;
            int k = kb + rr;
            Ws[rr][c] = (k < K) ? W[(size_t)k * N + c] : 0.f;
        }
        __syncthreads();
        #pragma unroll
        for (int kk = 0; kk < 16; kk++) {
            float4 a = *(const float4*)&As[kk][ty * 4];
            float4 b = *(const float4*)&Ws[kk][tx * 4];
            float av[4] = { a.x, a.y, a.z, a.w };
            float bv[4] = { b.x, b.y, b.z, b.w };
            #pragma unroll
            for (int i2 = 0; i2 < 4; i2++)
            #pragma unroll
            for (int j = 0; j < 4; j++)
                acc[i2][j] += av[i2] * bv[j];
        }
        __syncthreads();
    }
    #pragma unroll
    for (int i = 0; i < 4; i++) {
        int m = m0 + ty * 4 + i;
        #pragma unroll
        for (int j = 0; j < 4; j++) {
            int n = tx * 4 + j;
            float v = fmaxf(acc[i][j] + bias[n], 0.f);
            Cout[(size_t)m * N + n] = __float2bfloat16(v);
        }
    }
}

// ---------------- weight prep: f32 [K][256] -> bf16 [256][Kpad] -------------
__global__ __launch_bounds__(256) void k_prepw(const float* __restrict__ W2,
                                               const float* __restrict__ Wd0,
                                               const float* __restrict__ Wd1,
                                               short* __restrict__ Wt2,
                                               short* __restrict__ Wt3,
                                               short* __restrict__ Wt4) {
    int i = blockIdx.x * 256 + threadIdx.x;
    if (i < 256*64) {
        int n = i >> 6, k = i & 63;
        Wt2[i] = f2bf_bits(W2[(size_t)k*256 + n]);
        return;
    }
    i -= 256*64;
    if (i < 256*320) {
        int n = i / 320, k = i % 320;
        Wt3[i] = f2bf_bits(k < 283 ? Wd0[(size_t)k*256 + n] : 0.f);
        return;
    }
    i -= 256*320;
    if (i < 256*576) {
        int n = i / 576, k = i % 576;
        Wt4[i] = f2bf_bits(k < 539 ? Wd1[(size_t)k*256 + n] : 0.f);
    }
}

// ---------------- staging chunk loader (8 bf16 = 16B) ------------------------
template<int LAYER>
__device__ inline short8 load_chunk(const short* __restrict__ A0,
                                    const short* __restrict__ A1,
                                    const float* __restrict__ de,
                                    int m, int k) {
    if constexpr (LAYER == 2) {
        return *(const short8*)(A0 + (size_t)m * 64 + k);
    } else if constexpr (LAYER == 3) {
        if (k < 256) return *(const short8*)(A0 + (size_t)m * 256 + k);
        short8 v;
        int ray = m >> 5;
        #pragma unroll
        for (int j = 0; j < 8; j++) {
            int kk = k + j - 256;
            v[j] = f2bf_bits((kk < 27) ? de[ray * 27 + kk] : 0.f);
        }
        return v;
    } else {
        if (k < 256) return *(const short8*)(A0 + (size_t)m * 256 + k);
        if (k < 512) return *(const short8*)(A1 + (size_t)m * 256 + (k - 256));
        short8 v;
        int ray = m >> 5;
        #pragma unroll
        for (int j = 0; j < 8; j++) {
            int kk = k + j - 512;
            v[j] = f2bf_bits((kk < 27) ? de[ray * 27 + kk] : 0.f);
        }
        return v;
    }
}

// ---------------- MFMA MLP layer: [NP][K] @ Wt[256][Kp] -> [NP][256] ---------
template<int LAYER>
__global__ __launch_bounds__(256) void k_mlp(const short* __restrict__ A0,
                                             const short* __restrict__ A1,
                                             const float* __restrict__ de,
                                             const short* __restrict__ Wt,
                                             const float* __restrict__ bias,
                                             short* __restrict__ Cout,
                                             float* __restrict__ dens) {
    constexpr int KP = (LAYER == 2) ? 64 : (LAYER == 3) ? 320 : 576;
    __shared__ __align__(16) char As[8192];   // 64 rows x 64 k bf16, XOR-swizzled
    int tid = threadIdx.x;
    int wid = tid >> 6, lane = tid & 63;
    int m0 = blockIdx.x * 64;
    int l15 = lane & 15, l4 = lane >> 4;

    f32x4 acc[4][4] = {};
    for (int kt = 0; kt < KP / 64; kt++) {
        #pragma unroll
        for (int i = 0; i < 2; i++) {
            int q = tid + i * 256;
            int m = q >> 3, k8 = q & 7;
            short8 v = load_chunk<LAYER>(A0, A1, de, m0 + m, kt * 64 + k8 * 8);
            *(short8*)(As + ((m * 128 + k8 * 16) ^ ((m & 7) << 4))) = v;
        }
        __syncthreads();
        #pragma unroll
        for (int ks = 0; ks < 2; ks++) {
            short8 bfr[4], afr[4];
            #pragma unroll
            for (int nf = 0; nf < 4; nf++)
                bfr[nf] = *(const short8*)(Wt + (size_t)(wid * 64 + nf * 16 + l15) * KP
                                              + kt * 64 + ks * 32 + l4 * 8);
            #pragma unroll
            for (int mf = 0; mf < 4; mf++) {
                int m = mf * 16 + l15;
                afr[mf] = *(const short8*)(As + ((m * 128 + (ks * 4 + l4) * 16) ^ ((m & 7) << 4)));
            }
            #pragma unroll
            for (int mf = 0; mf < 4; mf++)
            #pragma unroll
            for (int nf = 0; nf < 4; nf++)
                acc[mf][nf] = __builtin_amdgcn_mfma_f32_16x16x32_bf16(afr[mf], bfr[nf], acc[mf][nf], 0, 0, 0);
        }
        __syncthreads();
    }

    #pragma unroll
    for (int mf = 0; mf < 4; mf++) {
        #pragma unroll
        for (int nf = 0; nf < 4; nf++) {
            int col = wid * 64 + nf * 16 + l15;
            float b = bias[col];
            #pragma unroll
            for (int r = 0; r < 4; r++) {
                int row = m0 + mf * 16 + l4 * 4 + r;
                float v = acc[mf][nf][r] + b;
                if constexpr (LAYER == 2) {
                    if (col == 0) {
                        float t = v - 1.f;
                        dens[(size_t)row * 4] = (t > 20.f) ? t : log1pf(expf(t));
                    }
                } else {
                    v = fmaxf(v, 0.f);
                }
                Cout[(size_t)row * 256 + col] = f2bf_bits(v);
            }
        }
    }
}

// ---------------- rgb layer: wave per point, shuffle reduce ------------------
__global__ __launch_bounds__(256) void k_rgb(const short* __restrict__ y1,
                                             const float* __restrict__ Wrgb,
                                             const float* __restrict__ brgb,
                                             float* __restrict__ out) {
    typedef __attribute__((ext_vector_type(4))) short short4v;
    int lane = threadIdx.x & 63;
    int p = blockIdx.x * 4 + (threadIdx.x >> 6);
    short4v yv = *(const short4v*)(y1 + (size_t)p * 256 + lane * 4);
    float y[4];
    #pragma unroll
    for (int j = 0; j < 4; j++) {
        unsigned u = ((unsigned)(unsigned short)yv[j]) << 16;
        y[j] = __builtin_bit_cast(float, u);
    }
    float4 w0 = *(const float4*)(Wrgb + lane * 12);
    float4 w1 = *(const float4*)(Wrgb + lane * 12 + 4);
    float4 w2 = *(const float4*)(Wrgb + lane * 12 + 8);
    float wf[12] = { w0.x, w0.y, w0.z, w0.w, w1.x, w1.y, w1.z, w1.w, w2.x, w2.y, w2.z, w2.w };
    float a0 = 0.f, a1 = 0.f, a2 = 0.f;
    #pragma unroll
    for (int j = 0; j < 4; j++) {
        a0 += y[j] * wf[j*3 + 0];
        a1 += y[j] * wf[j*3 + 1];
        a2 += y[j] * wf[j*3 + 2];
    }
    #pragma unroll
    for (int off = 32; off > 0; off >>= 1) {
        a0 += __shfl_xor(a0, off);
        a1 += __shfl_xor(a1, off);
        a2 += __shfl_xor(a2, off);
    }
    if (lane == 0) {
        float s0 = 1.f / (1.f + expf(-(a0 + brgb[0])));
        float s1 = 1.f / (1.f + expf(-(a1 + brgb[1])));
        float s2 = 1.f / (1.f + expf(-(a2 + brgb[2])));
        out[(size_t)p * 4 + 1] = s0 * 1.002f - 0.001f;
        out[(size_t)p * 4 + 2] = s1 * 1.002f - 0.001f;
        out[(size_t)p * 4 + 3] = s2 * 1.002f - 0.001f;
    }
}

extern "C" void kernel_launch(void* const* d_in, const int* in_sizes, int n_in,
                              void* d_out, int out_size, void* d_ws, size_t ws_size,
                              hipStream_t stream) {
    const float* means = (const float*)d_in[0];
    const float* stds  = (const float*)d_in[1];
    const float* vd    = (const float*)d_in[2];
    const float* table = (const float*)d_in[3];
    const float* W1    = (const float*)d_in[4];
    const float* b1    = (const float*)d_in[5];
    const float* W2    = (const float*)d_in[6];
    const float* b2    = (const float*)d_in[7];
    const float* Wd0   = (const float*)d_in[8];
    const float* bd0   = (const float*)d_in[9];
    const float* Wd1   = (const float*)d_in[10];
    const float* bd1   = (const float*)d_in[11];
    const float* Wrgb  = (const float*)d_in[12];
    const float* brgb  = (const float*)d_in[13];
    float* out = (float*)d_out;

    char* ws = (char*)d_ws;
    float4* ctr   = (float4*)(ws);                 // 786432*16  = 12,582,912 (dead after encode)
    float4* feats = (float4*)(ws + 12582912);      // 20,971,520
    float*  de    = (float*) (ws + 33554432);      //    442,368
    short*  h1    = (short*) (ws + 33996800);      // 16,777,216
    short*  x     = (short*) (ws + 50774016);      // 67,108,864
    short*  y0    = (short*) (ws + 117882880);     // 67,108,864
    short*  y1    = (short*) (ws + 184991744);     // 67,108,864
    // bf16 weights live in the (dead-after-encode) ctr region
    short*  Wt2   = (short*)(ws);                  //  32,768
    short*  Wt3   = (short*)(ws + 32768);          // 163,840
    short*  Wt4   = (short*)(ws + 196608);         // 294,912
    // bf16 hash table (levels 3..9, 7*2^21*8B = 117,440,512) overlays x/y0:
    // written by k_prept, read only by k_encode<3,true>; x/y0 are written
    // strictly after encode completes (stream-ordered), so no conflict.
    ushort4* tblH = (ushort4*)(ws + 50774016);

    k_contract<<<dim3(NPS/256), 256, 0, stream>>>(means, stds, ctr);
    k_prept<<<dim3(28672), 256, 0, stream>>>(table, tblH);
    k_encode<0,false><<<dim3(NP/256, HLV0), 256, 0, stream>>>(ctr, table, tblH, feats);
    k_encode<HLV0,true><<<dim3(NP/256, NHL), 256, 0, stream>>>(ctr, table, tblH, feats);
    k_dirs<<<dim3(NR/64), 64, 0, stream>>>(vd, de);
    k_prepw<<<dim3(960), 256, 0, stream>>>(W2, Wd0, Wd1, Wt2, Wt3, Wt4);
    k_l1<<<dim3(NP/64), 256, 0, stream>>>((const float*)feats, W1, b1, (bf16*)h1);
    k_mlp<2><<<dim3(NP/64), 256, 0, stream>>>(h1, nullptr, nullptr, Wt2, b2, x, out);
    k_mlp<3><<<dim3(NP/64), 256, 0, stream>>>(x, nullptr, de, Wt3, bd0, y0, nullptr);
    k_mlp<4><<<dim3(NP/64), 256, 0, stream>>>(y0, x, de, Wt4, bd1, y1, nullptr);
    k_rgb<<<dim3(NP/4), 256, 0, stream>>>(y1, Wrgb, brgb, out);
}